// Round 1
// 315.464 us; speedup vs baseline: 1.0174x; 1.0174x over previous
//
#include <hip/hip_runtime.h>

// out[b,c,h,w] = block_switch[h/8, w/8] ? -1.0f : image[b,c,h,w]
// image: [64, 3, 512, 512] fp32 ; block_switch: [64, 64] (bool -> int32 per harness)
//
// One float4 per lane per unroll step. A float4 starts at w = 4*k; 4k..4k+3
// share the same w/8 block (4k % 8 is 0 or 4) -> one mask lookup per float4.
//
// v2 changes vs v1 (320.96 us total, kernel ~78 us of it):
//  - 4-way unroll, block-stride (idx, idx+256, ...): 4 independent
//    mask->image load chains per wave -> 4x memory-level parallelism.
//    v1 had ONE outstanding HBM read per wave (image load was
//    control-dependent on the mask load), leaving read latency exposed.
//  - nontemporal load/store on the streaming image/out traffic (never
//    re-read); mask stays normally cached (16 KB, heavily reused).
//  - conditional image load KEPT: skipping masked 32B blocks saves ~25%
//    of 64B read sectors (P(both blocks in a sector masked) = 0.25).

typedef float f32x4 __attribute__((ext_vector_type(4)));

#define W 512
#define H 512
#define MASK_W 64      // W / 8
#define TPB 256
#define UNROLL 4

__global__ __launch_bounds__(TPB) void grid_crop_kernel(
    const f32x4* __restrict__ img,
    const int* __restrict__ mask,
    f32x4* __restrict__ out,
    int n4)
{
    int base = blockIdx.x * (TPB * UNROLL) + threadIdx.x;

    // Phase 1: issue all 4 mask loads (independent, L1-resident after warmup).
    int m[UNROLL];
#pragma unroll
    for (int u = 0; u < UNROLL; ++u) {
        int idx  = base + u * TPB;
        int elem = idx << 2;                 // flat float index
        int w    = elem & (W - 1);           // 0..511
        int h    = (elem >> 9) & (H - 1);    // 0..511  (W == 512 == 2^9)
        m[u] = (idx < n4) ? mask[(h >> 3) * MASK_W + (w >> 3)] : 1;
    }

    // Phase 2: 4 independent exec-masked image loads -> all in flight at once.
    f32x4 v[UNROLL];
#pragma unroll
    for (int u = 0; u < UNROLL; ++u) {
        int idx = base + u * TPB;
        if (m[u] == 0) {
            v[u] = __builtin_nontemporal_load(&img[idx]);
        } else {
            v[u] = (f32x4){-1.0f, -1.0f, -1.0f, -1.0f};
        }
    }

    // Phase 3: dense streaming stores.
#pragma unroll
    for (int u = 0; u < UNROLL; ++u) {
        int idx = base + u * TPB;
        if (idx < n4) {
            __builtin_nontemporal_store(v[u], &out[idx]);
        }
    }
}

extern "C" void kernel_launch(void* const* d_in, const int* in_sizes, int n_in,
                              void* d_out, int out_size, void* d_ws, size_t ws_size,
                              hipStream_t stream) {
    const f32x4* img  = (const f32x4*)d_in[0];
    const int*   mask = (const int*)d_in[1];
    f32x4*       out  = (f32x4*)d_out;

    int n4 = out_size >> 2;              // 64*3*512*512 / 4 = 12,582,912 float4
    int per_block = TPB * UNROLL;        // 1024 float4 per block
    int grid = (n4 + per_block - 1) / per_block;   // 12,288 blocks (exact)

    grid_crop_kernel<<<grid, TPB, 0, stream>>>(img, mask, out, n4);
}